// Round 1
// baseline (83.690 us; speedup 1.0000x reference)
//
#include <hip/hip_runtime.h>
#include <hip/hip_bf16.h>

#define BH 128
#define L 1024
#define D 64
#define MASK_VALUE -1000000.0f
#define KVBLK 64

typedef __attribute__((ext_vector_type(8))) __bf16 bf16x8;
typedef __attribute__((ext_vector_type(4))) float f32x4;
typedef __attribute__((ext_vector_type(4))) unsigned int u32x4;

__device__ __forceinline__ unsigned short f2bf(float f) {
    __bf16 h = (__bf16)f;
    return __builtin_bit_cast(unsigned short, h);
}

__device__ __forceinline__ f32x4 mfma16(bf16x8 a, bf16x8 b, f32x4 c) {
    return __builtin_amdgcn_mfma_f32_16x16x32_bf16(a, b, c, 0, 0, 0);
}

// LDS tile rows are 128 bytes; XOR-swizzle 16B slots by (row&7) to kill
// the stride-128B bank conflict on ds_read_b128 (G4).
__device__ __forceinline__ bf16x8 ldsfrag(const unsigned char* base, int row, int colbytes) {
    const u32x4* p = (const u32x4*)(base + row * 128 + (colbytes ^ ((row & 7) << 4)));
    return __builtin_bit_cast(bf16x8, *p);
}

__global__ __launch_bounds__(512)
void attn_kernel(const float* __restrict__ Q, const float* __restrict__ K,
                 const float* __restrict__ V, const int* __restrict__ vlen,
                 float* __restrict__ Out) {
    __shared__ __align__(16) unsigned char Kl[2][64 * 128];
    __shared__ __align__(16) unsigned char Vl[2][64 * 128];  // V transposed: row=d, col=k
    __shared__ __align__(16) unsigned char Pl[8][16 * 128];  // per-wave P tile

    const int tid  = threadIdx.x;
    const int lane = tid & 63;
    const int wid  = tid >> 6;
    const int bid  = blockIdx.x;
    const int head = bid >> 3;
    const int qt   = bid & 7;

    const int valid = vlen[head];
    const int nkt   = (valid == 0) ? (L / KVBLK) : ((valid + KVBLK - 1) >> 6);

    const float* Qh = Q + (size_t)head * L * D;
    const float* Kh = K + (size_t)head * L * D;
    const float* Vh = V + (size_t)head * L * D;
    float*       Oh = Out + (size_t)head * L * D;

    const int qrow0 = qt * 128 + wid * 16;
    const int qr    = lane & 15;          // col-in-fragment / row-in-A
    const int c8    = (lane >> 4) * 8;    // k-chunk base within fragment

    // ---- load Q fragments once (scale by 1/sqrt(64)=0.125, exact in bf16) ----
    bf16x8 qf[2];
#pragma unroll
    for (int kk = 0; kk < 2; ++kk) {
        const float* qp = Qh + (qrow0 + qr) * D + kk * 32 + c8;
        f32x4 a = *(const f32x4*)qp;
        f32x4 b = *(const f32x4*)(qp + 4);
        bf16x8 f;
        f[0] = (__bf16)(a[0] * 0.125f); f[1] = (__bf16)(a[1] * 0.125f);
        f[2] = (__bf16)(a[2] * 0.125f); f[3] = (__bf16)(a[3] * 0.125f);
        f[4] = (__bf16)(b[0] * 0.125f); f[5] = (__bf16)(b[1] * 0.125f);
        f[6] = (__bf16)(b[2] * 0.125f); f[7] = (__bf16)(b[3] * 0.125f);
        qf[kk] = f;
    }

    // ---- staging assignments ----
    const int skr = tid >> 3;         // K tile row (k pos), 0..63
    const int skc = (tid & 7) * 8;    // K tile col (d), 8 f32 per thread
    const int svk = tid & 63;         // V tile row (k pos)
    const int svd = (tid >> 6) * 8;   // V tile col base (d), 8 f32 per thread

    f32x4 rk0, rk1, rv0, rv1;

    auto load_regs = [&](int kt) {
        const float* kp = Kh + (size_t)(kt * KVBLK + skr) * D + skc;
        rk0 = *(const f32x4*)kp;
        rk1 = *(const f32x4*)(kp + 4);
        const float* vp = Vh + (size_t)(kt * KVBLK + svk) * D + svd;
        rv0 = *(const f32x4*)vp;
        rv1 = *(const f32x4*)(vp + 4);
    };

    auto write_lds = [&](int buf) {
        // K: row-major [k][d], 8 bf16 -> one ds_write_b128 (swizzled)
        unsigned char* kb = Kl[buf];
        u32x4 w;
        w[0] = (unsigned)f2bf(rk0[0]) | ((unsigned)f2bf(rk0[1]) << 16);
        w[1] = (unsigned)f2bf(rk0[2]) | ((unsigned)f2bf(rk0[3]) << 16);
        w[2] = (unsigned)f2bf(rk1[0]) | ((unsigned)f2bf(rk1[1]) << 16);
        w[3] = (unsigned)f2bf(rk1[2]) | ((unsigned)f2bf(rk1[3]) << 16);
        *(u32x4*)(kb + skr * 128 + ((skc * 2) ^ ((skr & 7) << 4))) = w;
        // V: transposed [d][k], 8 scalar b16 writes (2 lanes/bank -> free)
        unsigned char* vb = Vl[buf];
        float vv[8] = {rv0[0], rv0[1], rv0[2], rv0[3], rv1[0], rv1[1], rv1[2], rv1[3]};
#pragma unroll
        for (int j = 0; j < 8; ++j) {
            int row = svd + j;
            *(unsigned short*)(vb + row * 128 + ((svk * 2) ^ ((row & 7) << 4))) = f2bf(vv[j]);
        }
    };

    // ---- online softmax state ----
    f32x4 o[4];
#pragma unroll
    for (int t = 0; t < 4; ++t) { o[t][0] = 0.f; o[t][1] = 0.f; o[t][2] = 0.f; o[t][3] = 0.f; }
    float m_run[4] = {-INFINITY, -INFINITY, -INFINITY, -INFINITY};
    float l_run[4] = {0.f, 0.f, 0.f, 0.f};

    load_regs(0);
    write_lds(0);
    __syncthreads();

    for (int kt = 0; kt < nkt; ++kt) {
        const int  cur      = kt & 1;
        const bool has_next = (kt + 1 < nkt);
        if (has_next) load_regs(kt + 1);  // issue early; latency hides under compute

        // ---- S = Q K^T for 16 q-rows x 64 k-cols ----
        f32x4 s[4];
#pragma unroll
        for (int st = 0; st < 4; ++st) {
            bf16x8 kf0 = ldsfrag(Kl[cur], st * 16 + qr, c8 * 2);
            bf16x8 kf1 = ldsfrag(Kl[cur], st * 16 + qr, (32 + c8) * 2);
            f32x4 acc; acc[0] = 0.f; acc[1] = 0.f; acc[2] = 0.f; acc[3] = 0.f;
            acc = mfma16(qf[0], kf0, acc);
            acc = mfma16(qf[1], kf1, acc);
            s[st] = acc;
        }

        // ---- key-padding mask (col = kt*64 + st*16 + qr, uniform over rows) ----
        const int kbase = kt * KVBLK + qr;
#pragma unroll
        for (int st = 0; st < 4; ++st) {
            if (kbase + st * 16 >= valid) {
                s[st][0] = MASK_VALUE; s[st][1] = MASK_VALUE;
                s[st][2] = MASK_VALUE; s[st][3] = MASK_VALUE;
            }
        }

        // ---- online softmax: row max over 4 subtiles + 16 lanes ----
        float tm[4];
#pragma unroll
        for (int r = 0; r < 4; ++r)
            tm[r] = fmaxf(fmaxf(s[0][r], s[1][r]), fmaxf(s[2][r], s[3][r]));
#pragma unroll
        for (int off = 1; off < 16; off <<= 1) {
#pragma unroll
            for (int r = 0; r < 4; ++r)
                tm[r] = fmaxf(tm[r], __shfl_xor(tm[r], off));
        }

        float alpha[4], mnew[4], ps[4];
#pragma unroll
        for (int r = 0; r < 4; ++r) {
            mnew[r]  = fmaxf(m_run[r], tm[r]);
            alpha[r] = __expf(m_run[r] - mnew[r]);  // first tile: exp(-inf)=0
            m_run[r] = mnew[r];
            ps[r]    = 0.f;
        }

        // ---- P = exp(S - m), write to per-wave LDS tile (C-layout -> A-layout) ----
        unsigned char* pb = Pl[wid];
#pragma unroll
        for (int st = 0; st < 4; ++st) {
#pragma unroll
            for (int r = 0; r < 4; ++r) {
                float p = __expf(s[st][r] - mnew[r]);
                ps[r] += p;
                int row  = (lane >> 4) * 4 + r;
                int colb = (st * 16 + qr) * 2;
                *(unsigned short*)(pb + row * 128 + (colb ^ ((row & 7) << 4))) = f2bf(p);
            }
        }

        // row-sum reduce across the 16 lanes holding this row's columns
#pragma unroll
        for (int off = 1; off < 16; off <<= 1) {
#pragma unroll
            for (int r = 0; r < 4; ++r)
                ps[r] += __shfl_xor(ps[r], off);
        }
#pragma unroll
        for (int r = 0; r < 4; ++r)
            l_run[r] = l_run[r] * alpha[r] + ps[r];

        // rescale O
#pragma unroll
        for (int t = 0; t < 4; ++t) {
#pragma unroll
            for (int r = 0; r < 4; ++r)
                o[t][r] *= alpha[r];
        }

        // same-wave LDS RAW: enforce write->read order past TBAA
        asm volatile("s_waitcnt lgkmcnt(0)" ::: "memory");

        // ---- O += P V ----
        bf16x8 pf0 = ldsfrag(Pl[wid], qr, c8 * 2);
        bf16x8 pf1 = ldsfrag(Pl[wid], qr, (32 + c8) * 2);
#pragma unroll
        for (int t = 0; t < 4; ++t) {
            bf16x8 vf0 = ldsfrag(Vl[cur], t * 16 + qr, c8 * 2);
            bf16x8 vf1 = ldsfrag(Vl[cur], t * 16 + qr, (32 + c8) * 2);
            o[t] = mfma16(pf0, vf0, o[t]);
            o[t] = mfma16(pf1, vf1, o[t]);
        }

        if (has_next) write_lds((kt + 1) & 1);
        __syncthreads();
    }

    // ---- epilogue: normalize and store ----
    float rl[4];
#pragma unroll
    for (int r = 0; r < 4; ++r) rl[r] = 1.0f / l_run[r];
#pragma unroll
    for (int t = 0; t < 4; ++t) {
#pragma unroll
        for (int r = 0; r < 4; ++r) {
            int row = (lane >> 4) * 4 + r;
            int d   = t * 16 + qr;
            Oh[(size_t)(qrow0 + row) * D + d] = o[t][r] * rl[r];
        }
    }
}

extern "C" void kernel_launch(void* const* d_in, const int* in_sizes, int n_in,
                              void* d_out, int out_size, void* d_ws, size_t ws_size,
                              hipStream_t stream) {
    const float* Q    = (const float*)d_in[0];
    const float* K    = (const float*)d_in[1];
    const float* V    = (const float*)d_in[2];
    const int*   vlen = (const int*)d_in[3];
    float*       Out  = (float*)d_out;

    dim3 grid(BH * (L / 128));  // 1024 blocks: 8 q-tiles per head, head-major
    attn_kernel<<<grid, 512, 0, stream>>>(Q, K, V, vlen, Out);
}

// Round 2
// 64.360 us; speedup vs baseline: 1.3003x; 1.3003x over previous
//
#include <hip/hip_runtime.h>
#include <hip/hip_bf16.h>

#define BH 128
#define L 1024
#define D 64
#define MASK_VALUE -1000000.0f
#define KVBLK 64
#define RESCALE_THR 8.0f

typedef __attribute__((ext_vector_type(8))) __bf16 bf16x8;
typedef __attribute__((ext_vector_type(4))) float f32x4;
typedef __attribute__((ext_vector_type(4))) unsigned int u32x4;
typedef __attribute__((ext_vector_type(4))) unsigned short u16x4;

__device__ __forceinline__ unsigned short f2bf(float f) {
    __bf16 h = (__bf16)f;
    return __builtin_bit_cast(unsigned short, h);
}

__device__ __forceinline__ float exp2_asm(float x) {
    float r; asm("v_exp_f32 %0, %1" : "=v"(r) : "v"(x)); return r;
}

__device__ __forceinline__ f32x4 mfma16(bf16x8 a, bf16x8 b, f32x4 c) {
    return __builtin_amdgcn_mfma_f32_16x16x32_bf16(a, b, c, 0, 0, 0);
}

// LDS tile rows are 128 bytes; XOR-swizzle 16B slots by (row&7) to kill
// the stride-128B bank conflict on ds_read_b128 (G4).
__device__ __forceinline__ bf16x8 ldsfrag(const unsigned char* base, int row, int colbytes) {
    const u32x4* p = (const u32x4*)(base + row * 128 + (colbytes ^ ((row & 7) << 4)));
    return __builtin_bit_cast(bf16x8, *p);
}

__global__ __launch_bounds__(512)
void attn_kernel(const float* __restrict__ Q, const float* __restrict__ K,
                 const float* __restrict__ V, const int* __restrict__ vlen,
                 float* __restrict__ Out) {
    __shared__ __align__(16) unsigned char Kl[2][64 * 128];
    __shared__ __align__(16) unsigned char Vl[2][64 * 128];  // V transposed: row=d, col=k
    __shared__ __align__(16) unsigned char Pl[8][16 * 128];  // per-wave P tile [q][k]

    const int tid  = threadIdx.x;
    const int lane = tid & 63;
    const int wid  = tid >> 6;

    // XCD swizzle: all 8 q-tiles of a head on one XCD (bid%8 presumed = XCD)
    const int bid  = blockIdx.x;
    const int xcd  = bid & 7;
    const int grp  = bid >> 3;
    const int head = xcd * 16 + (grp & 15);
    const int qt   = grp >> 4;

    const int valid = vlen[head];
    const int nkt   = (valid == 0) ? (L / KVBLK) : ((valid + KVBLK - 1) >> 6);

    const float* Qh = Q + (size_t)head * L * D;
    const float* Kh = K + (size_t)head * L * D;
    const float* Vh = V + (size_t)head * L * D;
    float*       Oh = Out + (size_t)head * L * D;

    const int qrow0 = qt * 128 + wid * 16;
    const int q16   = lane & 15;          // q (as B-col) / frag row index
    const int hi    = lane >> 4;          // k-chunk group
    const int c8    = hi * 8;             // element chunk base within fragment

    // ---- load Q fragments once; scale folds 1/sqrt(64) * log2(e) for base-2 softmax ----
    const float QSCALE = 0.125f * 1.44269504088896f;
    bf16x8 qf[2];
#pragma unroll
    for (int kk = 0; kk < 2; ++kk) {
        const float* qp = Qh + (qrow0 + q16) * D + kk * 32 + c8;
        f32x4 a = *(const f32x4*)qp;
        f32x4 b = *(const f32x4*)(qp + 4);
        bf16x8 f;
        f[0] = (__bf16)(a[0] * QSCALE); f[1] = (__bf16)(a[1] * QSCALE);
        f[2] = (__bf16)(a[2] * QSCALE); f[3] = (__bf16)(a[3] * QSCALE);
        f[4] = (__bf16)(b[0] * QSCALE); f[5] = (__bf16)(b[1] * QSCALE);
        f[6] = (__bf16)(b[2] * QSCALE); f[7] = (__bf16)(b[3] * QSCALE);
        qf[kk] = f;
    }

    // ---- staging assignments ----
    const int skr = tid >> 3;         // K tile row (k pos), 0..63
    const int skc = (tid & 7) * 8;    // K tile col (d), 8 f32 per thread
    const int svk = tid & 63;         // V tile row (k pos)
    const int svd = (tid >> 6) * 8;   // V tile col base (d), 8 f32 per thread

    f32x4 rk0, rk1, rv0, rv1;

    auto load_regs = [&](int kt) {
        const float* kp = Kh + (size_t)(kt * KVBLK + skr) * D + skc;
        rk0 = *(const f32x4*)kp;
        rk1 = *(const f32x4*)(kp + 4);
        const float* vp = Vh + (size_t)(kt * KVBLK + svk) * D + svd;
        rv0 = *(const f32x4*)vp;
        rv1 = *(const f32x4*)(vp + 4);
    };

    auto write_lds = [&](int buf) {
        // K: row-major [k][d], 8 bf16 -> one ds_write_b128 (swizzled)
        unsigned char* kb = Kl[buf];
        u32x4 w;
        w[0] = (unsigned)f2bf(rk0[0]) | ((unsigned)f2bf(rk0[1]) << 16);
        w[1] = (unsigned)f2bf(rk0[2]) | ((unsigned)f2bf(rk0[3]) << 16);
        w[2] = (unsigned)f2bf(rk1[0]) | ((unsigned)f2bf(rk1[1]) << 16);
        w[3] = (unsigned)f2bf(rk1[2]) | ((unsigned)f2bf(rk1[3]) << 16);
        *(u32x4*)(kb + skr * 128 + ((skc * 2) ^ ((skr & 7) << 4))) = w;
        // V: transposed [d][k], 8 scalar b16 writes (2 lanes/bank -> free)
        unsigned char* vb = Vl[buf];
        float vv[8] = {rv0[0], rv0[1], rv0[2], rv0[3], rv1[0], rv1[1], rv1[2], rv1[3]};
#pragma unroll
        for (int j = 0; j < 8; ++j) {
            int row = svd + j;
            *(unsigned short*)(vb + row * 128 + ((svk * 2) ^ ((row & 7) << 4))) = f2bf(vv[j]);
        }
    };

    // ---- online softmax state (base-2; lane-local for q = q16) ----
    f32x4 o[4];
#pragma unroll
    for (int t = 0; t < 4; ++t) { o[t][0] = 0.f; o[t][1] = 0.f; o[t][2] = 0.f; o[t][3] = 0.f; }
    float m_run = -INFINITY;
    float l_run = 0.f;

    load_regs(0);
    write_lds(0);
    __syncthreads();

    for (int kt = 0; kt < nkt; ++kt) {
        const int  cur      = kt & 1;
        const bool has_next = (kt + 1 < nkt);
        if (has_next) load_regs(kt + 1);  // issue early; latency hides under compute

        // ---- S^T = K Q^T (swapped): lane holds S[k = st*16+hi*4+r][q = q16] ----
        f32x4 s[4];
        __builtin_amdgcn_s_setprio(1);
#pragma unroll
        for (int st = 0; st < 4; ++st) {
            bf16x8 kf0 = ldsfrag(Kl[cur], st * 16 + q16, c8 * 2);
            bf16x8 kf1 = ldsfrag(Kl[cur], st * 16 + q16, (32 + c8) * 2);
            f32x4 acc; acc[0] = 0.f; acc[1] = 0.f; acc[2] = 0.f; acc[3] = 0.f;
            acc = mfma16(kf0, qf[0], acc);
            acc = mfma16(kf1, qf[1], acc);
            s[st] = acc;
        }
        __builtin_amdgcn_s_setprio(0);

        // ---- key-padding mask (only when tile extends past valid; wave-uniform branch) ----
        if ((kt + 1) * KVBLK > valid) {
            const int kb = kt * KVBLK + hi * 4;
#pragma unroll
            for (int st = 0; st < 4; ++st)
#pragma unroll
                for (int r = 0; r < 4; ++r)
                    if (kb + st * 16 + r >= valid) s[st][r] = MASK_VALUE;
        }

        // ---- row max: in-lane tree over 16 + 2 shuffle rounds ----
        float t0 = fmaxf(fmaxf(s[0][0], s[0][1]), fmaxf(s[0][2], s[0][3]));
        float t1 = fmaxf(fmaxf(s[1][0], s[1][1]), fmaxf(s[1][2], s[1][3]));
        float t2 = fmaxf(fmaxf(s[2][0], s[2][1]), fmaxf(s[2][2], s[2][3]));
        float t3 = fmaxf(fmaxf(s[3][0], s[3][1]), fmaxf(s[3][2], s[3][3]));
        float tm = fmaxf(fmaxf(t0, t1), fmaxf(t2, t3));
        tm = fmaxf(tm, __shfl_xor(tm, 16));
        tm = fmaxf(tm, __shfl_xor(tm, 32));

        // ---- defer-max (T13): rescale only when max grew past THR ----
        if (!__all(tm <= m_run + RESCALE_THR)) {
            float mnew  = fmaxf(m_run, tm);
            float alpha = exp2_asm(m_run - mnew);  // first tile: exp2(-inf)=0
            l_run *= alpha;
            if (kt > 0) {  // O is zero on first tile; skip the gather+rescale
                float a0 = __shfl(alpha, hi * 4 + 0);
                float a1 = __shfl(alpha, hi * 4 + 1);
                float a2 = __shfl(alpha, hi * 4 + 2);
                float a3 = __shfl(alpha, hi * 4 + 3);
#pragma unroll
                for (int t = 0; t < 4; ++t) {
                    o[t][0] *= a0; o[t][1] *= a1; o[t][2] *= a2; o[t][3] *= a3;
                }
            }
            m_run = mnew;
        }

        // ---- P = exp2(S - m) in place; in-lane sum + 2 shuffle rounds ----
#pragma unroll
        for (int st = 0; st < 4; ++st)
#pragma unroll
            for (int r = 0; r < 4; ++r)
                s[st][r] = exp2_asm(s[st][r] - m_run);

        float u0 = (s[0][0] + s[0][1]) + (s[0][2] + s[0][3]);
        float u1 = (s[1][0] + s[1][1]) + (s[1][2] + s[1][3]);
        float u2 = (s[2][0] + s[2][1]) + (s[2][2] + s[2][3]);
        float u3 = (s[3][0] + s[3][1]) + (s[3][2] + s[3][3]);
        float lsum = (u0 + u1) + (u2 + u3);
        lsum += __shfl_xor(lsum, 16);
        lsum += __shfl_xor(lsum, 32);
        l_run += lsum;

        // ---- P -> per-wave LDS tile [q][k], 4 packed b64 writes (k consecutive) ----
        unsigned char* pb = Pl[wid];
#pragma unroll
        for (int st = 0; st < 4; ++st) {
            u16x4 w;
            w[0] = f2bf(s[st][0]); w[1] = f2bf(s[st][1]);
            w[2] = f2bf(s[st][2]); w[3] = f2bf(s[st][3]);
            *(u16x4*)(pb + q16 * 128 + ((st * 32 + hi * 8) ^ ((q16 & 7) << 4))) = w;
        }

        // same-wave LDS RAW: enforce write->read order past TBAA
        asm volatile("s_waitcnt lgkmcnt(0)" ::: "memory");

        // ---- O += P V ----
        bf16x8 pf0 = ldsfrag(pb, q16, c8 * 2);
        bf16x8 pf1 = ldsfrag(pb, q16, (32 + c8) * 2);
        __builtin_amdgcn_s_setprio(1);
#pragma unroll
        for (int t = 0; t < 4; ++t) {
            bf16x8 vf0 = ldsfrag(Vl[cur], t * 16 + q16, c8 * 2);
            bf16x8 vf1 = ldsfrag(Vl[cur], t * 16 + q16, (32 + c8) * 2);
            o[t] = mfma16(pf0, vf0, o[t]);
            o[t] = mfma16(pf1, vf1, o[t]);
        }
        __builtin_amdgcn_s_setprio(0);

        if (has_next) write_lds((kt + 1) & 1);
        __syncthreads();
    }

    // ---- epilogue: gather 1/l for this lane's 4 q-rows, normalize, store ----
    float linv = 1.0f / l_run;
    float r0 = __shfl(linv, hi * 4 + 0);
    float r1 = __shfl(linv, hi * 4 + 1);
    float r2 = __shfl(linv, hi * 4 + 2);
    float r3 = __shfl(linv, hi * 4 + 3);
#pragma unroll
    for (int t = 0; t < 4; ++t) {
        const int d = t * 16 + q16;
        Oh[(size_t)(qrow0 + hi * 4 + 0) * D + d] = o[t][0] * r0;
        Oh[(size_t)(qrow0 + hi * 4 + 1) * D + d] = o[t][1] * r1;
        Oh[(size_t)(qrow0 + hi * 4 + 2) * D + d] = o[t][2] * r2;
        Oh[(size_t)(qrow0 + hi * 4 + 3) * D + d] = o[t][3] * r3;
    }
}

extern "C" void kernel_launch(void* const* d_in, const int* in_sizes, int n_in,
                              void* d_out, int out_size, void* d_ws, size_t ws_size,
                              hipStream_t stream) {
    const float* Q    = (const float*)d_in[0];
    const float* K    = (const float*)d_in[1];
    const float* V    = (const float*)d_in[2];
    const int*   vlen = (const int*)d_in[3];
    float*       Out  = (float*)d_out;

    dim3 grid(BH * (L / 128));  // 1024 blocks: 8 q-tiles per head
    attn_kernel<<<grid, 512, 0, stream>>>(Q, K, V, vlen, Out);
}